// Round 14
// baseline (153.556 us; speedup 1.0000x reference)
//
#include <hip/hip_runtime.h>

#define BATCH   256
#define NFEAT   20000
#define NVEC    (NFEAT / 4)
#define KSEL    256
#define NSAMP   8
#define SEL_REPS 13

typedef unsigned long long u64;
typedef float __attribute__((ext_vector_type(4))) f32x4;

// Map float bits to unsigned key with same total order as float compare.
__device__ __forceinline__ unsigned fmap(float f) {
    unsigned u = __float_as_uint(f);
    return (u & 0x80000000u) ? ~u : (u | 0x80000000u);
}

// Fast pick over exactly 64 entries (arr[63] = highest bin), wave 0 only.
__device__ __forceinline__ void pick64(const unsigned* arr, int w, int lane,
                                       int* s_idx, int* s_w) {
    unsigned c = arr[63 - lane];
    unsigned p = c;
#pragma unroll
    for (int off = 1; off < 64; off <<= 1) {
        unsigned t = __shfl_up(p, off);
        if (lane >= off) p += t;
    }
    unsigned long long m = __ballot(p >= (unsigned)w);
    if (m) {
        int l = __ffsll(m) - 1;
        if (lane == l) { *s_idx = 63 - l; *s_w = w - (int)(p - c); }
    } else if (lane == 0) { *s_idx = 0; *s_w = 1; }   // unreachable safety
}

// R13 select + built-in rep loop (idempotent; every rep computes the same
// threshold). Rep 0 is the cold pass; reps 1..reps-1 measure the warm cost.
// Per-rep warm time = (dispatch_dur - cold) / (reps-1); counters land in the
// rocprof top-5 because dispatch > 96 us.
__global__ __launch_bounds__(1024) void topk_select(const float* __restrict__ logits,
                                                    u64* __restrict__ rowthr, int reps) {
    const int b = blockIdx.x, tid = threadIdx.x;
    const int lane = tid & 63, wave = tid >> 6;
    const float4* __restrict__ row4 = (const float4*)(logits + (size_t)b * NFEAT);

    __shared__ unsigned hist[4096];     // 16 KB
    __shared__ unsigned csum[64];
    __shared__ int s_d, s_w;
    __shared__ u64 s_thr;
    __shared__ int s_run, s_cut, s_wc[16];

    int zero = 0;                        // opaque 0: defeats hoist/CSE across reps
#pragma unroll 1
    for (int r = 0; r < reps; ++r) {
        asm volatile("" : "+v"(zero));

        // ---- Phase 1: 5 independent global loads, zero hist, histogram ----
        float4 v[5];
#pragma unroll
        for (int j = 0; j < 5; ++j) {
            const int i4 = tid + j * 1024 + zero;
            v[j] = row4[(i4 < NVEC) ? i4 : (NVEC - 1)];
        }
#pragma unroll
        for (int j = 0; j < 4; ++j) hist[tid + j * 1024] = 0;
        __syncthreads();

        unsigned kk[5][4];
#pragma unroll
        for (int j = 0; j < 5; ++j) {
            kk[j][0] = fmap(v[j].x); kk[j][1] = fmap(v[j].y);
            kk[j][2] = fmap(v[j].z); kk[j][3] = fmap(v[j].w);
        }
#pragma unroll
        for (int j = 0; j < 4; ++j) {
#pragma unroll
            for (int e = 0; e < 4; ++e) atomicAdd(&hist[kk[j][e] >> 20], 1u);
        }
        if (tid + 4096 < NVEC) {
#pragma unroll
            for (int e = 0; e < 4; ++e) atomicAdd(&hist[kk[4][e] >> 20], 1u);
        }
        __syncthreads();

        // ---- Phase 2: hierarchical 4096-bin pick ----
        unsigned P; int w;
        {
#pragma unroll
            for (int j = 0; j < 4; ++j) {
                const int cc = wave * 4 + j;
                unsigned x = hist[cc * 64 + lane];
#pragma unroll
                for (int off = 32; off; off >>= 1) x += __shfl_down(x, off);
                if (lane == 0) csum[cc] = x;
            }
            __syncthreads();
            if (wave == 0) pick64(csum, KSEL, lane, &s_d, &s_w);
            __syncthreads();
            const int chunk = s_d; const int w0 = s_w;
            if (wave == 0) pick64(&hist[chunk * 64], w0, lane, &s_d, &s_w);
            __syncthreads();
            P = (unsigned)(chunk * 64 + s_d);
            w = s_w;
        }
        unsigned cnt = hist[P];
        int shift = 20;

        // ---- Phase 3: register-sourced radix refine, early exit ----
        while (cnt > 1u && shift > 0) {
            const int nb  = (shift >= 8) ? 8 : shift;
            const int nsh = shift - nb;
            const int NB  = 1 << nb;
            const int nz  = (NB > 64) ? NB : 64;
            __syncthreads();
            if (tid < nz) hist[tid] = 0;
            if (tid >= 4 && tid < 64) csum[tid] = 0;
            __syncthreads();

#pragma unroll
            for (int j = 0; j < 5; ++j) {
                const int i4 = tid + j * 1024;
                if (i4 < NVEC) {
#pragma unroll
                    for (int e = 0; e < 4; ++e) {
                        const unsigned k = kk[j][e];
                        if ((k >> shift) == P)
                            atomicAdd(&hist[(k >> nsh) & (unsigned)(NB - 1)], 1u);
                    }
                }
            }
            __syncthreads();

            unsigned d;
            if (NB > 64) {
                if (wave < 4) {
                    unsigned x = hist[wave * 64 + lane];
#pragma unroll
                    for (int off = 32; off; off >>= 1) x += __shfl_down(x, off);
                    if (lane == 0) csum[wave] = x;
                }
                __syncthreads();
                if (wave == 0) pick64(csum, w, lane, &s_d, &s_w);
                __syncthreads();
                const int chunk2 = s_d; const int w1 = s_w;
                if (wave == 0) pick64(&hist[chunk2 * 64], w1, lane, &s_d, &s_w);
                __syncthreads();
                d = (unsigned)(chunk2 * 64 + s_d);
            } else {
                if (wave == 0) pick64(hist, w, lane, &s_d, &s_w);
                __syncthreads();
                d = (unsigned)s_d;
            }
            w = s_w;
            cnt = hist[d];
            P = (P << nb) | d;
            shift = nsh;
        }

        // ---- Phase 4: emit threshold ----
        if (cnt == 1u) {
#pragma unroll
            for (int j = 0; j < 5; ++j) {
                const int i4 = tid + j * 1024;
                if (i4 < NVEC) {
#pragma unroll
                    for (int e = 0; e < 4; ++e) {
                        const unsigned k = kk[j][e];
                        if ((k >> shift) == P)
                            s_thr = ((u64)k << 32) | (unsigned)~(4 * i4 + e);
                    }
                }
            }
            __syncthreads();
        } else {
            // shift==0, cnt>1 exact-duplicate keys: ordered ballot scan.
            if (tid == 0) { s_run = 0; s_cut = 0; }
            __syncthreads();
#pragma unroll 1
            for (int j = 0; j < 5; ++j) {
                const int i4 = tid + j * 1024;
                bool eq[4];
                int cnt4 = 0;
#pragma unroll
                for (int e = 0; e < 4; ++e) {
                    eq[e] = (i4 < NVEC) && (kk[j][e] == P);
                    cnt4 += eq[e] ? 1 : 0;
                }
                unsigned p = (unsigned)cnt4;
#pragma unroll
                for (int off = 1; off < 64; off <<= 1) {
                    unsigned t = __shfl_up(p, off);
                    if (lane >= off) p += t;
                }
                const unsigned excl = p - (unsigned)cnt4;
                if (lane == 63) s_wc[wave] = (int)p;
                __syncthreads();
                int off0 = s_run + (int)excl;
                for (int x = 0; x < wave; ++x) off0 += s_wc[x];
#pragma unroll
                for (int e = 0; e < 4; ++e) {
                    if (eq[e]) { if (off0 == w - 1) s_cut = 4 * i4 + e; ++off0; }
                }
                __syncthreads();
                if (tid == 0) { int t = 0; for (int x = 0; x < 16; ++x) t += s_wc[x]; s_run += t; }
                __syncthreads();
                if (s_run >= w) break;
            }
            if (tid == 0) s_thr = ((u64)P << 32) | (unsigned)~s_cut;
            __syncthreads();
        }

        if (tid == 0) rowthr[b] = s_thr;
        __syncthreads();
        asm volatile("" ::: "memory");
    }
}

// Wide-grid writer (proven): each thread reads one float4 of logits,
// computes 4 mask values, writes to all 8 sample slices.
__global__ __launch_bounds__(256) void write_out(const float* __restrict__ logits,
                                                 const u64* __restrict__ rowthr,
                                                 float* __restrict__ out) {
    const int b = blockIdx.y;
    const int q = blockIdx.x * 256 + threadIdx.x;   // index over N/4
    if (q >= NVEC) return;

    const u64 thr = rowthr[b];
    const unsigned thr_k = (unsigned)(thr >> 32);
    const unsigned thr_l = (unsigned)thr;
    const int n = q * 4;
    const float4 v = *reinterpret_cast<const float4*>(logits + (size_t)b * NFEAT + n);

    f32x4 m;
    {
        const float* vf = &v.x;
#pragma unroll
        for (int j = 0; j < 4; ++j) {
            const unsigned k = fmap(vf[j]);
            const bool sel = (k > thr_k) || (k == thr_k && (unsigned)~(n + j) >= thr_l);
            m[j] = sel ? 1.0f : 0.0f;
        }
    }

#pragma unroll
    for (int s = 0; s < NSAMP; ++s) {
        *reinterpret_cast<f32x4*>(out + ((size_t)s * BATCH + b) * NFEAT + n) = m;
    }
}

extern "C" void kernel_launch(void* const* d_in, const int* in_sizes, int n_in,
                              void* d_out, int out_size, void* d_ws, size_t ws_size,
                              hipStream_t stream) {
    const float* logits = (const float*)d_in[0];
    float* out = (float*)d_out;
    u64* rowthr = (u64*)d_ws;   // 256 * 8 B = 2 KB

    topk_select<<<BATCH, 1024, 0, stream>>>(logits, rowthr, SEL_REPS);

    dim3 grid((NVEC + 255) / 256, BATCH);
    write_out<<<grid, 256, 0, stream>>>(logits, rowthr, out);
}

// Round 15
// 35.898 us; speedup vs baseline: 4.2776x; 4.2776x over previous
//
#include <hip/hip_runtime.h>

#define BATCH   256
#define NFEAT   20000
#define NVEC    (NFEAT / 4)     // 5000
#define KSEL    256
#define NSAMP   8
#define SELT    512             // select threads (waves 0-7)
#define NBATCH  10              // ceil(NVEC / SELT)

typedef unsigned long long u64;
typedef float __attribute__((ext_vector_type(4))) f32x4;

__device__ __forceinline__ unsigned fmap(float f) {
    unsigned u = __float_as_uint(f);
    return (u & 0x80000000u) ? ~u : (u | 0x80000000u);
}

// Fast pick over exactly 64 entries (arr[63] = highest bin), wave 0 only.
__device__ __forceinline__ void pick64(const unsigned* arr, int w, int lane,
                                       int* s_idx, int* s_w) {
    unsigned c = arr[63 - lane];
    unsigned p = c;
#pragma unroll
    for (int off = 1; off < 64; off <<= 1) {
        unsigned t = __shfl_up(p, off);
        if (lane >= off) p += t;
    }
    unsigned long long m = __ballot(p >= (unsigned)w);
    if (m) {
        int l = __ffsll(m) - 1;
        if (lane == l) { *s_idx = 63 - l; *s_w = w - (int)(p - c); }
    } else if (lane == 0) { *s_idx = 0; *s_w = 1; }
}

// Spin barrier for a fixed group of `nw` waves (LDS counter, workgroup scope).
// Each call: every wave's lane 0 arrives; all spin until the phase completes.
__device__ __forceinline__ void group_bar(int* ctr, int lane, int* phase, int nw) {
    *phase += nw;
    if (lane == 0)
        __hip_atomic_fetch_add(ctr, 1, __ATOMIC_ACQ_REL, __HIP_MEMORY_SCOPE_WORKGROUP);
    while (__hip_atomic_load(ctr, __ATOMIC_ACQUIRE, __HIP_MEMORY_SCOPE_WORKGROUP) < *phase)
        __builtin_amdgcn_s_sleep(1);
}

// One block per row. Waves 0-7: top-K select (512 thr, 40 reg keys each,
// LDS spin barriers only). Waves 8-15: stream zeros for the row's 8 output
// slices immediately (overlapping the select), drain, then write the K
// published indices as 1.0. No s_barrier after the init one => writer
// store-backpressure never stalls the select.
__global__ __launch_bounds__(1024) void topk_ws(const float* __restrict__ logits,
                                                float* __restrict__ out) {
    const int b = blockIdx.x, tid = threadIdx.x;
    const int lane = tid & 63;
    const size_t BN = (size_t)BATCH * NFEAT;
    float* const outb = out + (size_t)b * NFEAT;

    __shared__ unsigned hist[4096];     // 16 KB (select only)
    __shared__ unsigned csum[64];
    __shared__ unsigned idxlist[SELT];
    __shared__ int s_d, s_w;
    __shared__ u64 s_thr;
    __shared__ unsigned s_nidx;
    __shared__ int s_selbar, s_wrbar, s_flag;
    __shared__ int s_run, s_cut, s_wc[8];

    if (tid == 0) { s_selbar = 0; s_wrbar = 0; s_flag = 0; s_nidx = 0; }
    __syncthreads();   // the ONLY full-block barrier

    if (tid < SELT) {
        // ======================= SELECT: waves 0-7 =======================
        const int t = tid;
        const int wave = t >> 6;            // 0..7
        int ph = 0;
        const float4* __restrict__ row4 = (const float4*)(logits + (size_t)b * NFEAT);

        // ---- Phase 1: loads (10 x float4), zero hist, histogram ----
        float4 v[NBATCH];
#pragma unroll
        for (int j = 0; j < NBATCH; ++j) {
            const int i4 = t + j * SELT;
            v[j] = row4[(i4 < NVEC) ? i4 : (NVEC - 1)];
        }
#pragma unroll
        for (int j = 0; j < 8; ++j) hist[t + j * SELT] = 0;

        unsigned kk[NBATCH][4];
#pragma unroll
        for (int j = 0; j < NBATCH; ++j) {
            kk[j][0] = fmap(v[j].x); kk[j][1] = fmap(v[j].y);
            kk[j][2] = fmap(v[j].z); kk[j][3] = fmap(v[j].w);
        }
        group_bar(&s_selbar, lane, &ph, 8);

#pragma unroll
        for (int j = 0; j < NBATCH; ++j) {
            const int i4 = t + j * SELT;
            if (i4 < NVEC) {
#pragma unroll
                for (int e = 0; e < 4; ++e) atomicAdd(&hist[kk[j][e] >> 20], 1u);
            }
        }
        group_bar(&s_selbar, lane, &ph, 8);

        // ---- Phase 2: hierarchical 4096-bin pick (8 chunks per wave) ----
        unsigned P; int w;
        {
#pragma unroll
            for (int jj = 0; jj < 8; ++jj) {
                const int cc = wave * 8 + jj;
                unsigned x = hist[cc * 64 + lane];
#pragma unroll
                for (int off = 32; off; off >>= 1) x += __shfl_down(x, off);
                if (lane == 0) csum[cc] = x;
            }
            group_bar(&s_selbar, lane, &ph, 8);
            if (wave == 0) pick64(csum, KSEL, lane, &s_d, &s_w);
            group_bar(&s_selbar, lane, &ph, 8);
            const int chunk = s_d; const int w0 = s_w;
            if (wave == 0) pick64(&hist[chunk * 64], w0, lane, &s_d, &s_w);
            group_bar(&s_selbar, lane, &ph, 8);
            P = (unsigned)(chunk * 64 + s_d);
            w = s_w;
        }
        unsigned cnt = hist[P];
        int shift = 20;

        // ---- Phase 3: register-sourced radix refine, early exit ----
        while (cnt > 1u && shift > 0) {
            const int nb  = (shift >= 8) ? 8 : shift;
            const int nsh = shift - nb;
            const int NB  = 1 << nb;
            const int nz  = (NB > 64) ? NB : 64;
            group_bar(&s_selbar, lane, &ph, 8);    // all cnt reads done
            for (int i = t; i < nz; i += SELT) hist[i] = 0;
            if (t >= 4 && t < 64) csum[t] = 0;
            group_bar(&s_selbar, lane, &ph, 8);

#pragma unroll
            for (int j = 0; j < NBATCH; ++j) {
                const int i4 = t + j * SELT;
                if (i4 < NVEC) {
#pragma unroll
                    for (int e = 0; e < 4; ++e) {
                        const unsigned k = kk[j][e];
                        if ((k >> shift) == P)
                            atomicAdd(&hist[(k >> nsh) & (unsigned)(NB - 1)], 1u);
                    }
                }
            }
            group_bar(&s_selbar, lane, &ph, 8);

            unsigned d;
            if (NB > 64) {
                if (wave < 4) {
                    unsigned x = hist[wave * 64 + lane];
#pragma unroll
                    for (int off = 32; off; off >>= 1) x += __shfl_down(x, off);
                    if (lane == 0) csum[wave] = x;
                }
                group_bar(&s_selbar, lane, &ph, 8);
                if (wave == 0) pick64(csum, w, lane, &s_d, &s_w);
                group_bar(&s_selbar, lane, &ph, 8);
                const int c2 = s_d; const int w1 = s_w;
                if (wave == 0) pick64(&hist[c2 * 64], w1, lane, &s_d, &s_w);
                group_bar(&s_selbar, lane, &ph, 8);
                d = (unsigned)(c2 * 64 + s_d);
            } else {
                if (wave == 0) pick64(hist, w, lane, &s_d, &s_w);
                group_bar(&s_selbar, lane, &ph, 8);
                d = (unsigned)s_d;
            }
            w = s_w;
            cnt = hist[d];
            P = (P << nb) | d;
            shift = nsh;
        }

        // ---- Phase 4: emit threshold ----
        if (cnt == 1u) {
#pragma unroll
            for (int j = 0; j < NBATCH; ++j) {
                const int i4 = t + j * SELT;
                if (i4 < NVEC) {
#pragma unroll
                    for (int e = 0; e < 4; ++e) {
                        const unsigned k = kk[j][e];
                        if ((k >> shift) == P)
                            s_thr = ((u64)k << 32) | (unsigned)~(4 * i4 + e);
                    }
                }
            }
            group_bar(&s_selbar, lane, &ph, 8);
        } else {
            // shift==0, duplicate keys (unreachable for this data): ordered scan.
            if (t == 0) { s_run = 0; s_cut = 0; }
            group_bar(&s_selbar, lane, &ph, 8);
#pragma unroll 1
            for (int j = 0; j < NBATCH; ++j) {
                const int i4 = t + j * SELT;
                bool eq[4];
                int cnt4 = 0;
#pragma unroll
                for (int e = 0; e < 4; ++e) {
                    eq[e] = (i4 < NVEC) && (kk[j][e] == P);
                    cnt4 += eq[e] ? 1 : 0;
                }
                unsigned p = (unsigned)cnt4;
#pragma unroll
                for (int off = 1; off < 64; off <<= 1) {
                    unsigned tt = __shfl_up(p, off);
                    if (lane >= off) p += tt;
                }
                const unsigned excl = p - (unsigned)cnt4;
                if (lane == 63) s_wc[wave] = (int)p;
                group_bar(&s_selbar, lane, &ph, 8);
                int off0 = s_run + (int)excl;
                for (int x = 0; x < wave; ++x) off0 += s_wc[x];
#pragma unroll
                for (int e = 0; e < 4; ++e) {
                    if (eq[e]) { if (off0 == w - 1) s_cut = 4 * i4 + e; ++off0; }
                }
                group_bar(&s_selbar, lane, &ph, 8);
                if (t == 0) { int s = 0; for (int x = 0; x < 8; ++x) s += s_wc[x]; s_run += s; }
                group_bar(&s_selbar, lane, &ph, 8);
                if (s_run >= w) break;
            }
            if (t == 0) s_thr = ((u64)P << 32) | (unsigned)~s_cut;
            group_bar(&s_selbar, lane, &ph, 8);
        }

        // ---- Publish selected indices + flag ----
        const u64 thr = s_thr;
        const unsigned thr_k = (unsigned)(thr >> 32);
        const unsigned thr_l = (unsigned)thr;
#pragma unroll
        for (int j = 0; j < NBATCH; ++j) {
            const int i4 = t + j * SELT;
            if (i4 < NVEC) {
#pragma unroll
                for (int e = 0; e < 4; ++e) {
                    const unsigned k = kk[j][e];
                    const int n = 4 * i4 + e;
                    const bool sel = (k > thr_k) || (k == thr_k && (unsigned)~n >= thr_l);
                    if (sel) {
                        unsigned pos = atomicAdd(&s_nidx, 1u);
                        idxlist[pos & (SELT - 1)] = (unsigned)n;
                    }
                }
            }
        }
        group_bar(&s_selbar, lane, &ph, 8);
        if (t == 0)
            __hip_atomic_store(&s_flag, 1, __ATOMIC_RELEASE, __HIP_MEMORY_SCOPE_WORKGROUP);
        // select waves done
    } else {
        // ======================= WRITER: waves 8-15 =======================
        const int t2 = tid - SELT;          // 0..511
        int ph = 0;
        const f32x4 z4 = {0.0f, 0.0f, 0.0f, 0.0f};

        // ---- stream zeros for all 8 slices of this row ----
#pragma unroll
        for (int s = 0; s < NSAMP; ++s) {
            float* const base = outb + (size_t)s * BN;
            for (int i = t2; i < NVEC; i += SELT)
                *reinterpret_cast<f32x4*>(base + 4 * i) = z4;
        }
        asm volatile("s_waitcnt vmcnt(0)" ::: "memory");   // zeros drained (this wave)
        group_bar(&s_wrbar, lane, &ph, 8);                 // all writer waves drained

        // ---- wait for the select result ----
        while (__hip_atomic_load(&s_flag, __ATOMIC_ACQUIRE, __HIP_MEMORY_SCOPE_WORKGROUP) == 0)
            __builtin_amdgcn_s_sleep(2);

        const unsigned nsel = s_nidx;       // == KSEL
        if (t2 < nsel) {
            const unsigned idx = idxlist[t2];
#pragma unroll
            for (int s = 0; s < NSAMP; ++s)
                outb[(size_t)s * BN + idx] = 1.0f;
        }
    }
}

extern "C" void kernel_launch(void* const* d_in, const int* in_sizes, int n_in,
                              void* d_out, int out_size, void* d_ws, size_t ws_size,
                              hipStream_t stream) {
    const float* logits = (const float*)d_in[0];
    float* out = (float*)d_out;
    (void)d_ws; (void)ws_size;

    topk_ws<<<BATCH, 1024, 0, stream>>>(logits, out);
}